// Round 11
// baseline (1366.771 us; speedup 1.0000x reference)
//
#include <hip/hip_runtime.h>

#define NN 50000
#define EE 800000
#define ITERS 20
#define KAPPA 0.99f
#define NTILES 3125        // NN/16
#define NCHUNK 4
#define CHROWS 12500       // NN/NCHUNK rows per chunk
#define NV (NN * NCHUNK)   // virtual columns
#define NB2 782            // ceil(NV/256)
#define SC_VRANGE (NV / 8) // 25000 vcols per scatter pass

typedef __bf16 bf16x8 __attribute__((ext_vector_type(8)));
typedef float f32x4 __attribute__((ext_vector_type(4)));
typedef unsigned short u16;
typedef unsigned int u32;

__device__ __forceinline__ u16 f2bf(float f) {
  u32 u = __float_as_uint(f);
  u32 r = u + 0x7FFFu + ((u >> 16) & 1u);
  return (u16)(r >> 16);
}
__device__ __forceinline__ u32 pack2bf(float a, float b) {
  return (u32)f2bf(a) | ((u32)f2bf(b) << 16);
}
__device__ __forceinline__ float bflo(u32 x) { return __uint_as_float(x << 16); }
__device__ __forceinline__ float bfhi(u32 x) { return __uint_as_float(x & 0xFFFF0000u); }

// ---------------- W projection (rows onto l1-ball of radius kappa) -> bf16 ----
__global__ __launch_bounds__(128)
void proj_w(const float* __restrict__ W, u16* __restrict__ Wb) {
  __shared__ float su[128];
  __shared__ float scs[128];
  __shared__ int sred[128];
  __shared__ float theta_s, rowsum_s;
  int row = blockIdx.x, t = threadIdx.x;
  float w = W[row * 128 + t];
  float aw = fabsf(w);
  su[t] = aw;
  __syncthreads();
  for (int k = 2; k <= 128; k <<= 1) {
    for (int j = k >> 1; j > 0; j >>= 1) {
      int ixj = t ^ j;
      if (ixj > t) {
        float a = su[t], b = su[ixj];
        if ((t & k) == 0) { if (a > b) { su[t] = b; su[ixj] = a; } }
        else              { if (a < b) { su[t] = b; su[ixj] = a; } }
      }
      __syncthreads();
    }
  }
  float ud = su[127 - t];
  scs[t] = ud;
  __syncthreads();
  for (int off = 1; off < 128; off <<= 1) {
    float v = (t >= off) ? scs[t - off] : 0.f;
    __syncthreads();
    scs[t] += v;
    __syncthreads();
  }
  float cs = scs[t] - KAPPA;
  sred[t] = ((ud - cs / (float)(t + 1)) > 0.f) ? 1 : 0;
  __syncthreads();
  for (int off = 64; off > 0; off >>= 1) {
    if (t < off) sred[t] += sred[t + off];
    __syncthreads();
  }
  if (t == 0) {
    int rho = sred[0] - 1;
    float th = (scs[rho] - KAPPA) / (float)(rho + 1);
    theta_s = fmaxf(th, 0.f);
    rowsum_s = scs[127];
  }
  __syncthreads();
  float outv;
  if (rowsum_s > KAPPA) {
    float pw = fmaxf(aw - theta_s, 0.f);
    outv = (w >= 0.f) ? pw : -pw;
  } else {
    outv = w;
  }
  Wb[row * 128 + t] = f2bf(outv);
}

// ---------------- two small f32 -> bf16 converts fused -----------------------
__global__ __launch_bounds__(256)
void convert_mat2(const float* __restrict__ a, const float* __restrict__ b,
                  u16* __restrict__ oa, u16* __restrict__ ob) {
  int i = blockIdx.x * 256 + threadIdx.x;
  if (i < 16384) oa[i] = f2bf(a[i]);
  else           ob[i - 16384] = f2bf(b[i - 16384]);
}

// ---------------- U (128 x N) -> Ub (N x 128 bf16) ---------------------------
__global__ __launch_bounds__(256)
void transpose_u(const float* __restrict__ U, u16* __restrict__ Ub, int Nn) {
  __shared__ u16 sh[64][130];
  int n0 = blockIdx.x * 64;
  int t = threadIdx.x;
  int nl = t & 63, pq = t >> 6;
  #pragma unroll
  for (int i = 0; i < 128; i += 4) {
    int p = i + pq;
    int n = n0 + nl;
    float v = (n < Nn) ? U[(size_t)p * Nn + n] : 0.f;
    sh[nl][p] = f2bf(v);
  }
  __syncthreads();
  #pragma unroll
  for (int j = 0; j < 16; ++j) {
    int node = j * 4 + pq;
    int n = n0 + node;
    if (n < Nn) {
      u32 lo = sh[node][nl * 2], hi = sh[node][nl * 2 + 1];
      ((u32*)Ub)[(size_t)n * 64 + nl] = lo | (hi << 16);
    }
  }
}

// ---------------- chunked-CSC build (vcol = col*4 + row/CHROWS) --------------
__global__ __launch_bounds__(256)
void hist_k(const int* __restrict__ rows, const int* __restrict__ cols,
            int* __restrict__ counts) {
  int i = blockIdx.x * 256 + threadIdx.x;
  u32 vc = (u32)cols[i] * NCHUNK + (u32)rows[i] / CHROWS;
  atomicAdd(&counts[vc], 1);
}

__global__ __launch_bounds__(256)
void scan1(const int* __restrict__ counts, int* __restrict__ bsums) {
  __shared__ int s[256];
  int t = threadIdx.x;
  int i = blockIdx.x * 256 + t;
  s[t] = (i < NV) ? counts[i] : 0;
  __syncthreads();
  for (int off = 128; off > 0; off >>= 1) {
    if (t < off) s[t] += s[t + off];
    __syncthreads();
  }
  if (t == 0) bsums[blockIdx.x] = s[0];
}

__global__ __launch_bounds__(1024)
void scan2(const int* __restrict__ bsums, int* __restrict__ boffs) {
  __shared__ int s[1024];
  int t = threadIdx.x;
  int v = (t < NB2) ? bsums[t] : 0;
  s[t] = v;
  __syncthreads();
  for (int off = 1; off < 1024; off <<= 1) {
    int u = (t >= off) ? s[t - off] : 0;
    __syncthreads();
    s[t] += u;
    __syncthreads();
  }
  if (t < NB2) boffs[t] = s[t] - v;   // exclusive
}

__global__ __launch_bounds__(256)
void scan3(const int* __restrict__ counts, const int* __restrict__ boffs,
           int* __restrict__ colptr, int* __restrict__ cursor) {
  __shared__ int s[256];
  int t = threadIdx.x;
  int i = blockIdx.x * 256 + t;
  int v = (i < NV) ? counts[i] : 0;
  s[t] = v;
  __syncthreads();
  for (int off = 1; off < 256; off <<= 1) {
    int u = (t >= off) ? s[t - off] : 0;
    __syncthreads();
    s[t] += u;
    __syncthreads();
  }
  int excl = s[t] - v + boffs[blockIdx.x];
  if (i < NV) { colptr[i] = excl; cursor[i] = excl; }
  if (i == 0) colptr[NV] = EE;
}

// 8 vcol-range passes, XCD-aligned (pass = blockIdx & 7)
__global__ __launch_bounds__(256)
void scatter_k(const int* __restrict__ rows, const int* __restrict__ cols,
               const float* __restrict__ vals, int* __restrict__ cursor,
               uint2* __restrict__ rv) {
  int pass = blockIdx.x & 7;
  int i = (blockIdx.x >> 3) * 256 + threadIdx.x;
  int r = rows[i];
  u32 vc = (u32)cols[i] * NCHUNK + (u32)r / CHROWS;
  u32 lo = pass * SC_VRANGE;
  if (vc - lo < SC_VRANGE) {
    int pos = atomicAdd(&cursor[vc], 1);
    rv[pos] = make_uint2((u32)r, __float_as_uint(vals[i]));
  }
}

// ---------------- GEMM: out[n][m] = sum_k Mat[m][k] * Xsrc[n][k] -------------
// One 16-node tile per wave, no loop; grid 782 x 4 waves covers 3125 tiles.
// launch_bounds(256,4) caps VGPR at 128 -> 16 waves/CU for latency hiding.
__global__ __launch_bounds__(256, 4)
void gemm_k(const u16* __restrict__ Mb, const u16* __restrict__ Xsrc,
            u32* __restrict__ outp) {
  int lane = threadIdx.x & 63;
  int wid = threadIdx.x >> 6;
  int r = lane & 15, kg = lane >> 4;
  int t = blockIdx.x * 4 + wid;
  if (t >= NTILES) return;
  // issue the long-latency X loads first
  const u16* xp = Xsrc + (size_t)(t * 16 + r) * 128 + kg * 8;
  bf16x8 xc[4];
  #pragma unroll
  for (int kk = 0; kk < 4; ++kk)
    xc[kk] = *reinterpret_cast<const bf16x8*>(xp + kk * 32);
  // W fragments (L2-hot broadcast)
  bf16x8 wf[8][4];
  #pragma unroll
  for (int mt = 0; mt < 8; ++mt)
    #pragma unroll
    for (int kk = 0; kk < 4; ++kk)
      wf[mt][kk] = *reinterpret_cast<const bf16x8*>(
          Mb + (mt * 16 + r) * 128 + kk * 32 + kg * 8);
  f32x4 acc[8];
  #pragma unroll
  for (int mt = 0; mt < 8; ++mt) acc[mt] = (f32x4)(0.f);
  #pragma unroll
  for (int mt = 0; mt < 8; ++mt)
    #pragma unroll
    for (int kk = 0; kk < 4; ++kk)
      acc[mt] = __builtin_amdgcn_mfma_f32_16x16x32_bf16(
          wf[mt][kk], xc[kk], acc[mt], 0, 0, 0);
  u32* o = outp + (size_t)(t * 16 + r) * 64 + kg * 2;
  #pragma unroll
  for (int mt = 0; mt < 8; ++mt) {
    uint2 pk;
    pk.x = pack2bf(acc[mt][0], acc[mt][1]);
    pk.y = pack2bf(acc[mt][2], acc[mt][3]);
    *reinterpret_cast<uint2*>(o + mt * 8) = pk;
  }
}

// ---------------- SpMM gather: 16-lane group per node ------------------------
// MODE 0: bias build  Bb += gather (no relu), write Bb packed bf16
// MODE 1: iteration   relu(gather + Bb) -> Xb packed bf16
// MODE 2: last iter   relu(gather + Bb) -> OutF feature-major fp32 (fused
//         transpose: out[m*NN+n]; block covers 16 consecutive n = full lines)
template<int MODE>
__global__ __launch_bounds__(256, 4)
void spmm_k(const int* __restrict__ colptr, const uint2* __restrict__ rv,
            const u16* __restrict__ Src, u32* __restrict__ Bb,
            u32* __restrict__ Xb, float* __restrict__ OutF) {
  int wid = threadIdx.x >> 6;
  int lane = threadIdx.x & 63;
  int l16 = lane & 15;
  int gb = lane & 48;                      // group base lane (g*16)
  int n = blockIdx.x * 16 + wid * 4 + (lane >> 4);
  int beg = colptr[n * NCHUNK];
  int deg = colptr[n * NCHUNK + NCHUNK] - beg;
  const u32* sp = (const u32*)Src + l16 * 4;
  uint4 bp = *(const uint4*)(Bb + (size_t)n * 64 + l16 * 4);  // hoisted
  float a0 = 0.f, a1 = 0.f, a2 = 0.f, a3 = 0.f;
  float a4 = 0.f, a5 = 0.f, a6 = 0.f, a7 = 0.f;
  for (int base = 0; base < deg; base += 16) {
    int cnt = deg - base; if (cnt > 16) cnt = 16;
    uint2 p = rv[beg + base + ((l16 < cnt) ? l16 : 0)];
    int rr = (int)p.x;
    float vv = __uint_as_float(p.y);
    #pragma unroll
    for (int h = 0; h < 2; ++h) {
      int j0 = h * 8;
      if (j0 < cnt) {
        int ri[8]; float vi[8]; uint4 xr[8];
        #pragma unroll
        for (int q = 0; q < 8; ++q) ri[q] = __shfl(rr, gb + j0 + q);
        #pragma unroll
        for (int q = 0; q < 8; ++q)
          xr[q] = *(const uint4*)(sp + (size_t)ri[q] * 64);
        #pragma unroll
        for (int q = 0; q < 8; ++q) {
          float f = __shfl(vv, gb + j0 + q);
          vi[q] = (j0 + q < cnt) ? f : 0.f;
        }
        #pragma unroll
        for (int q = 0; q < 8; ++q) {
          a0 += vi[q] * bflo(xr[q].x); a1 += vi[q] * bfhi(xr[q].x);
          a2 += vi[q] * bflo(xr[q].y); a3 += vi[q] * bfhi(xr[q].y);
          a4 += vi[q] * bflo(xr[q].z); a5 += vi[q] * bfhi(xr[q].z);
          a6 += vi[q] * bflo(xr[q].w); a7 += vi[q] * bfhi(xr[q].w);
        }
      }
    }
  }
  float o0 = a0 + bflo(bp.x), o1 = a1 + bfhi(bp.x);
  float o2 = a2 + bflo(bp.y), o3 = a3 + bfhi(bp.y);
  float o4 = a4 + bflo(bp.z), o5 = a5 + bfhi(bp.z);
  float o6 = a6 + bflo(bp.w), o7 = a7 + bfhi(bp.w);
  if (MODE >= 1) {
    o0 = fmaxf(o0, 0.f); o1 = fmaxf(o1, 0.f);
    o2 = fmaxf(o2, 0.f); o3 = fmaxf(o3, 0.f);
    o4 = fmaxf(o4, 0.f); o5 = fmaxf(o5, 0.f);
    o6 = fmaxf(o6, 0.f); o7 = fmaxf(o7, 0.f);
  }
  if (MODE <= 1) {
    uint4 pk;
    pk.x = pack2bf(o0, o1); pk.y = pack2bf(o2, o3);
    pk.z = pack2bf(o4, o5); pk.w = pack2bf(o6, o7);
    u32* dst = (MODE == 0) ? Bb : Xb;
    *(uint4*)(dst + (size_t)n * 64 + l16 * 4) = pk;
  } else {
    // fused transpose-out: feature-major fp32 writes
    float* o = OutF + (size_t)(l16 * 8) * NN + n;
    o[0]        = o0; o[NN]       = o1;
    o[2u * NN]  = o2; o[3u * NN]  = o3;
    o[4u * NN]  = o4; o[5u * NN]  = o5;
    o[6u * NN]  = o6; o[7u * NN]  = o7;
  }
}

// ---------------- launcher ---------------------------------------------------
extern "C" void kernel_launch(void* const* d_in, const int* in_sizes, int n_in,
                              void* d_out, int out_size, void* d_ws, size_t ws_size,
                              hipStream_t stream) {
  (void)in_sizes; (void)n_in; (void)out_size; (void)ws_size;
  const float* U   = (const float*)d_in[0];
  const int*   er  = (const int*)d_in[1];
  const int*   ec  = (const int*)d_in[2];
  const float* ev  = (const float*)d_in[3];
  const float* W   = (const float*)d_in[4];
  const float* Om1 = (const float*)d_in[5];
  const float* Om2 = (const float*)d_in[6];
  float* out = (float*)d_out;

  char* base = (char*)d_ws;
  size_t off = 0;
  auto alloc = [&](size_t b) {
    char* p = base + off;
    off = (off + b + 255) & ~(size_t)255;
    return p;
  };
  u16* Wb     = (u16*)alloc(128 * 128 * 2);
  u16* Om1b   = (u16*)alloc(128 * 128 * 2);
  u16* Om2b   = (u16*)alloc(128 * 128 * 2);
  u16* Ub     = (u16*)alloc((size_t)NN * 128 * 2);
  u32* Xb     = (u32*)alloc((size_t)NN * 64 * 4);
  u32* Xwb    = (u32*)alloc((size_t)NN * 64 * 4);
  u32* Bb     = (u32*)alloc((size_t)NN * 64 * 4);
  int* counts = (int*)alloc((size_t)NV * 4);
  int* colptr = (int*)alloc((size_t)(NV + 1) * 4);
  int* cursor = (int*)alloc((size_t)NV * 4);
  int* bsums  = (int*)alloc((size_t)NB2 * 4);
  int* boffs  = (int*)alloc((size_t)NB2 * 4);
  uint2* rv   = (uint2*)alloc((size_t)EE * 8);

  // setup: projection, converts, transpose, chunked-CSC build
  proj_w<<<dim3(128), dim3(128), 0, stream>>>(W, Wb);
  convert_mat2<<<dim3(128), dim3(256), 0, stream>>>(Om1, Om2, Om1b, Om2b);
  transpose_u<<<dim3((NN + 63) / 64), dim3(256), 0, stream>>>(U, Ub, NN);
  hipMemsetAsync(counts, 0, (size_t)NV * 4, stream);
  hist_k<<<dim3(EE / 256), dim3(256), 0, stream>>>(er, ec, counts);
  scan1<<<dim3(NB2), dim3(256), 0, stream>>>(counts, bsums);
  scan2<<<dim3(1), dim3(1024), 0, stream>>>(bsums, boffs);
  scan3<<<dim3(NB2), dim3(256), 0, stream>>>(counts, boffs, colptr, cursor);
  scatter_k<<<dim3(8 * (EE / 256)), dim3(256), 0, stream>>>(er, ec, ev, cursor, rv);

  // B = gather(Omega_1 @ U) + Omega_2 @ U  (Bb holds bf16 B); X_0 = B
  const int GB = (NTILES + 3) / 4;  // 782
  gemm_k<<<dim3(GB), dim3(256), 0, stream>>>(Om1b, Ub, Xwb);
  gemm_k<<<dim3(GB), dim3(256), 0, stream>>>(Om2b, Ub, Bb);
  spmm_k<0><<<dim3(NN / 16), dim3(256), 0, stream>>>(colptr, rv, (const u16*)Xwb,
                                                     Bb, (u32*)nullptr, (float*)nullptr);

  // 20 fixed-point iterations (X_0 = B lives in Bb for the first gemm)
  for (int it = 0; it < ITERS; ++it) {
    const u16* xsrc = (it == 0) ? (const u16*)Bb : (const u16*)Xb;
    gemm_k<<<dim3(GB), dim3(256), 0, stream>>>(Wb, xsrc, Xwb);
    if (it < ITERS - 1)
      spmm_k<1><<<dim3(NN / 16), dim3(256), 0, stream>>>(colptr, rv, (const u16*)Xwb,
                                                         Bb, Xb, (float*)nullptr);
    else
      spmm_k<2><<<dim3(NN / 16), dim3(256), 0, stream>>>(colptr, rv, (const u16*)Xwb,
                                                         Bb, (u32*)nullptr, out);
  }
}

// Round 14
// 1318.583 us; speedup vs baseline: 1.0365x; 1.0365x over previous
//
#include <hip/hip_runtime.h>

#define NN 50000
#define EE 800000
#define ITERS 20
#define KAPPA 0.99f
#define NTILES 3125        // NN/16
#define NCHUNK 4
#define CHROWS 12500       // NN/NCHUNK rows per chunk
#define NV (NN * NCHUNK)   // virtual columns
#define NB2 782            // ceil(NV/256)
#define SC_VRANGE (NV / 8) // 25000 vcols per scatter pass

typedef __bf16 bf16x8 __attribute__((ext_vector_type(8)));
typedef float f32x4 __attribute__((ext_vector_type(4)));
typedef unsigned short u16;
typedef unsigned int u32;

__device__ __forceinline__ u16 f2bf(float f) {
  u32 u = __float_as_uint(f);
  u32 r = u + 0x7FFFu + ((u >> 16) & 1u);
  return (u16)(r >> 16);
}
__device__ __forceinline__ u32 pack2bf(float a, float b) {
  return (u32)f2bf(a) | ((u32)f2bf(b) << 16);
}
__device__ __forceinline__ float bflo(u32 x) { return __uint_as_float(x << 16); }
__device__ __forceinline__ float bfhi(u32 x) { return __uint_as_float(x & 0xFFFF0000u); }

// ---------------- W projection (rows onto l1-ball of radius kappa) -> bf16 ----
__global__ __launch_bounds__(128)
void proj_w(const float* __restrict__ W, u16* __restrict__ Wb) {
  __shared__ float su[128];
  __shared__ float scs[128];
  __shared__ int sred[128];
  __shared__ float theta_s, rowsum_s;
  int row = blockIdx.x, t = threadIdx.x;
  float w = W[row * 128 + t];
  float aw = fabsf(w);
  su[t] = aw;
  __syncthreads();
  for (int k = 2; k <= 128; k <<= 1) {
    for (int j = k >> 1; j > 0; j >>= 1) {
      int ixj = t ^ j;
      if (ixj > t) {
        float a = su[t], b = su[ixj];
        if ((t & k) == 0) { if (a > b) { su[t] = b; su[ixj] = a; } }
        else              { if (a < b) { su[t] = b; su[ixj] = a; } }
      }
      __syncthreads();
    }
  }
  float ud = su[127 - t];
  scs[t] = ud;
  __syncthreads();
  for (int off = 1; off < 128; off <<= 1) {
    float v = (t >= off) ? scs[t - off] : 0.f;
    __syncthreads();
    scs[t] += v;
    __syncthreads();
  }
  float cs = scs[t] - KAPPA;
  sred[t] = ((ud - cs / (float)(t + 1)) > 0.f) ? 1 : 0;
  __syncthreads();
  for (int off = 64; off > 0; off >>= 1) {
    if (t < off) sred[t] += sred[t + off];
    __syncthreads();
  }
  if (t == 0) {
    int rho = sred[0] - 1;
    float th = (scs[rho] - KAPPA) / (float)(rho + 1);
    theta_s = fmaxf(th, 0.f);
    rowsum_s = scs[127];
  }
  __syncthreads();
  float outv;
  if (rowsum_s > KAPPA) {
    float pw = fmaxf(aw - theta_s, 0.f);
    outv = (w >= 0.f) ? pw : -pw;
  } else {
    outv = w;
  }
  Wb[row * 128 + t] = f2bf(outv);
}

// ---------------- two small f32 -> bf16 converts fused -----------------------
__global__ __launch_bounds__(256)
void convert_mat2(const float* __restrict__ a, const float* __restrict__ b,
                  u16* __restrict__ oa, u16* __restrict__ ob) {
  int i = blockIdx.x * 256 + threadIdx.x;
  if (i < 16384) oa[i] = f2bf(a[i]);
  else           ob[i - 16384] = f2bf(b[i - 16384]);
}

// ---------------- U (128 x N) -> Ub (N x 128 bf16) ---------------------------
__global__ __launch_bounds__(256)
void transpose_u(const float* __restrict__ U, u16* __restrict__ Ub, int Nn) {
  __shared__ u16 sh[64][130];
  int n0 = blockIdx.x * 64;
  int t = threadIdx.x;
  int nl = t & 63, pq = t >> 6;
  #pragma unroll
  for (int i = 0; i < 128; i += 4) {
    int p = i + pq;
    int n = n0 + nl;
    float v = (n < Nn) ? U[(size_t)p * Nn + n] : 0.f;
    sh[nl][p] = f2bf(v);
  }
  __syncthreads();
  #pragma unroll
  for (int j = 0; j < 16; ++j) {
    int node = j * 4 + pq;
    int n = n0 + node;
    if (n < Nn) {
      u32 lo = sh[node][nl * 2], hi = sh[node][nl * 2 + 1];
      ((u32*)Ub)[(size_t)n * 64 + nl] = lo | (hi << 16);
    }
  }
}

// ---------------- chunked-CSC build (vcol = col*4 + row/CHROWS) --------------
__global__ __launch_bounds__(256)
void hist_k(const int* __restrict__ rows, const int* __restrict__ cols,
            int* __restrict__ counts) {
  int i = blockIdx.x * 256 + threadIdx.x;
  u32 vc = (u32)cols[i] * NCHUNK + (u32)rows[i] / CHROWS;
  atomicAdd(&counts[vc], 1);
}

__global__ __launch_bounds__(256)
void scan1(const int* __restrict__ counts, int* __restrict__ bsums) {
  __shared__ int s[256];
  int t = threadIdx.x;
  int i = blockIdx.x * 256 + t;
  s[t] = (i < NV) ? counts[i] : 0;
  __syncthreads();
  for (int off = 128; off > 0; off >>= 1) {
    if (t < off) s[t] += s[t + off];
    __syncthreads();
  }
  if (t == 0) bsums[blockIdx.x] = s[0];
}

__global__ __launch_bounds__(1024)
void scan2(const int* __restrict__ bsums, int* __restrict__ boffs) {
  __shared__ int s[1024];
  int t = threadIdx.x;
  int v = (t < NB2) ? bsums[t] : 0;
  s[t] = v;
  __syncthreads();
  for (int off = 1; off < 1024; off <<= 1) {
    int u = (t >= off) ? s[t - off] : 0;
    __syncthreads();
    s[t] += u;
    __syncthreads();
  }
  if (t < NB2) boffs[t] = s[t] - v;   // exclusive
}

__global__ __launch_bounds__(256)
void scan3(const int* __restrict__ counts, const int* __restrict__ boffs,
           int* __restrict__ colptr, int* __restrict__ cursor) {
  __shared__ int s[256];
  int t = threadIdx.x;
  int i = blockIdx.x * 256 + t;
  int v = (i < NV) ? counts[i] : 0;
  s[t] = v;
  __syncthreads();
  for (int off = 1; off < 256; off <<= 1) {
    int u = (t >= off) ? s[t - off] : 0;
    __syncthreads();
    s[t] += u;
    __syncthreads();
  }
  int excl = s[t] - v + boffs[blockIdx.x];
  if (i < NV) { colptr[i] = excl; cursor[i] = excl; }
  if (i == 0) colptr[NV] = EE;
}

// 8 vcol-range passes, XCD-aligned (pass = blockIdx & 7)
__global__ __launch_bounds__(256)
void scatter_k(const int* __restrict__ rows, const int* __restrict__ cols,
               const float* __restrict__ vals, int* __restrict__ cursor,
               uint2* __restrict__ rv) {
  int pass = blockIdx.x & 7;
  int i = (blockIdx.x >> 3) * 256 + threadIdx.x;
  int r = rows[i];
  u32 vc = (u32)cols[i] * NCHUNK + (u32)r / CHROWS;
  u32 lo = pass * SC_VRANGE;
  if (vc - lo < SC_VRANGE) {
    int pos = atomicAdd(&cursor[vc], 1);
    rv[pos] = make_uint2((u32)r, __float_as_uint(vals[i]));
  }
}

// ---------------- GEMM: out[n][m] = sum_k Mat[m][k] * Xsrc[n][k] -------------
// 2 waves per 16-node tile; each wave computes 4 of the 8 m-tiles.
// Per-wave regs: xc[4](16) + acc[4](16) + transient wf[4](16) ~ 70 VGPR,
// fits the 128-cap of launch_bounds(256,4) -> 16 waves/CU, no spill.
__global__ __launch_bounds__(256, 4)
void gemm_k(const u16* __restrict__ Mb, const u16* __restrict__ Xsrc,
            u32* __restrict__ outp) {
  int lane = threadIdx.x & 63;
  int wid = threadIdx.x >> 6;
  int r = lane & 15, kg = lane >> 4;
  int t = blockIdx.x * 2 + (wid >> 1);
  int mh = wid & 1;                       // which half of the 8 m-tiles
  if (t >= NTILES) return;
  const u16* xp = Xsrc + (size_t)(t * 16 + r) * 128 + kg * 8;
  bf16x8 xc[4];
  #pragma unroll
  for (int kk = 0; kk < 4; ++kk)
    xc[kk] = *reinterpret_cast<const bf16x8*>(xp + kk * 32);
  f32x4 acc[4];
  #pragma unroll
  for (int j = 0; j < 4; ++j) acc[j] = (f32x4)(0.f);
  const u16* wp = Mb + (mh * 64 + r) * 128 + kg * 8;
  #pragma unroll
  for (int j = 0; j < 4; ++j) {
    bf16x8 wf[4];
    #pragma unroll
    for (int kk = 0; kk < 4; ++kk)
      wf[kk] = *reinterpret_cast<const bf16x8*>(wp + j * 16 * 128 + kk * 32);
    #pragma unroll
    for (int kk = 0; kk < 4; ++kk)
      acc[j] = __builtin_amdgcn_mfma_f32_16x16x32_bf16(wf[kk], xc[kk], acc[j], 0, 0, 0);
  }
  u32* o = outp + (size_t)(t * 16 + r) * 64 + kg * 2;
  #pragma unroll
  for (int j = 0; j < 4; ++j) {
    uint2 pk;
    pk.x = pack2bf(acc[j][0], acc[j][1]);
    pk.y = pack2bf(acc[j][2], acc[j][3]);
    *reinterpret_cast<uint2*>(o + (mh * 4 + j) * 8) = pk;
  }
}

// ---------------- SpMM gather: 16-lane group per node ------------------------
// MODE 0: bias build  Bb += gather (no relu), write Bb packed bf16
// MODE 1: iteration   relu(gather + Bb) -> Xb packed bf16
// MODE 2: last iter   relu(gather + Bb) -> OutF feature-major fp32 (fused
//         transpose: out[m*NN+n])
template<int MODE>
__global__ __launch_bounds__(256, 4)
void spmm_k(const int* __restrict__ colptr, const uint2* __restrict__ rv,
            const u16* __restrict__ Src, u32* __restrict__ Bb,
            u32* __restrict__ Xb, float* __restrict__ OutF) {
  int wid = threadIdx.x >> 6;
  int lane = threadIdx.x & 63;
  int l16 = lane & 15;
  int gb = lane & 48;                      // group base lane (g*16)
  int n = blockIdx.x * 16 + wid * 4 + (lane >> 4);
  int beg = colptr[n * NCHUNK];
  int deg = colptr[n * NCHUNK + NCHUNK] - beg;
  const u32* sp = (const u32*)Src + l16 * 4;
  uint4 bp = *(const uint4*)(Bb + (size_t)n * 64 + l16 * 4);  // hoisted
  float a0 = 0.f, a1 = 0.f, a2 = 0.f, a3 = 0.f;
  float a4 = 0.f, a5 = 0.f, a6 = 0.f, a7 = 0.f;
  for (int base = 0; base < deg; base += 16) {
    int cnt = deg - base; if (cnt > 16) cnt = 16;
    uint2 p = rv[beg + base + ((l16 < cnt) ? l16 : 0)];
    int rr = (int)p.x;
    float vv = __uint_as_float(p.y);
    #pragma unroll
    for (int h = 0; h < 2; ++h) {
      int j0 = h * 8;
      if (j0 < cnt) {
        int ri[8]; float vi[8]; uint4 xr[8];
        #pragma unroll
        for (int q = 0; q < 8; ++q) ri[q] = __shfl(rr, gb + j0 + q);
        #pragma unroll
        for (int q = 0; q < 8; ++q)
          xr[q] = *(const uint4*)(sp + (size_t)ri[q] * 64);
        #pragma unroll
        for (int q = 0; q < 8; ++q) {
          float f = __shfl(vv, gb + j0 + q);
          vi[q] = (j0 + q < cnt) ? f : 0.f;
        }
        #pragma unroll
        for (int q = 0; q < 8; ++q) {
          a0 += vi[q] * bflo(xr[q].x); a1 += vi[q] * bfhi(xr[q].x);
          a2 += vi[q] * bflo(xr[q].y); a3 += vi[q] * bfhi(xr[q].y);
          a4 += vi[q] * bflo(xr[q].z); a5 += vi[q] * bfhi(xr[q].z);
          a6 += vi[q] * bflo(xr[q].w); a7 += vi[q] * bfhi(xr[q].w);
        }
      }
    }
  }
  float o0 = a0 + bflo(bp.x), o1 = a1 + bfhi(bp.x);
  float o2 = a2 + bflo(bp.y), o3 = a3 + bfhi(bp.y);
  float o4 = a4 + bflo(bp.z), o5 = a5 + bfhi(bp.z);
  float o6 = a6 + bflo(bp.w), o7 = a7 + bfhi(bp.w);
  if (MODE >= 1) {
    o0 = fmaxf(o0, 0.f); o1 = fmaxf(o1, 0.f);
    o2 = fmaxf(o2, 0.f); o3 = fmaxf(o3, 0.f);
    o4 = fmaxf(o4, 0.f); o5 = fmaxf(o5, 0.f);
    o6 = fmaxf(o6, 0.f); o7 = fmaxf(o7, 0.f);
  }
  if (MODE <= 1) {
    uint4 pk;
    pk.x = pack2bf(o0, o1); pk.y = pack2bf(o2, o3);
    pk.z = pack2bf(o4, o5); pk.w = pack2bf(o6, o7);
    u32* dst = (MODE == 0) ? Bb : Xb;
    *(uint4*)(dst + (size_t)n * 64 + l16 * 4) = pk;
  } else {
    // fused transpose-out: feature-major fp32 writes
    float* o = OutF + (size_t)(l16 * 8) * NN + n;
    o[0]        = o0; o[NN]       = o1;
    o[2u * NN]  = o2; o[3u * NN]  = o3;
    o[4u * NN]  = o4; o[5u * NN]  = o5;
    o[6u * NN]  = o6; o[7u * NN]  = o7;
  }
}

// ---------------- launcher ---------------------------------------------------
extern "C" void kernel_launch(void* const* d_in, const int* in_sizes, int n_in,
                              void* d_out, int out_size, void* d_ws, size_t ws_size,
                              hipStream_t stream) {
  (void)in_sizes; (void)n_in; (void)out_size; (void)ws_size;
  const float* U   = (const float*)d_in[0];
  const int*   er  = (const int*)d_in[1];
  const int*   ec  = (const int*)d_in[2];
  const float* ev  = (const float*)d_in[3];
  const float* W   = (const float*)d_in[4];
  const float* Om1 = (const float*)d_in[5];
  const float* Om2 = (const float*)d_in[6];
  float* out = (float*)d_out;

  char* base = (char*)d_ws;
  size_t off = 0;
  auto alloc = [&](size_t b) {
    char* p = base + off;
    off = (off + b + 255) & ~(size_t)255;
    return p;
  };
  u16* Wb     = (u16*)alloc(128 * 128 * 2);
  u16* Om1b   = (u16*)alloc(128 * 128 * 2);
  u16* Om2b   = (u16*)alloc(128 * 128 * 2);
  u16* Ub     = (u16*)alloc((size_t)NN * 128 * 2);
  u32* Xb     = (u32*)alloc((size_t)NN * 64 * 4);
  u32* Xwb    = (u32*)alloc((size_t)NN * 64 * 4);
  u32* Bb     = (u32*)alloc((size_t)NN * 64 * 4);
  int* counts = (int*)alloc((size_t)NV * 4);
  int* colptr = (int*)alloc((size_t)(NV + 1) * 4);
  int* cursor = (int*)alloc((size_t)NV * 4);
  int* bsums  = (int*)alloc((size_t)NB2 * 4);
  int* boffs  = (int*)alloc((size_t)NB2 * 4);
  uint2* rv   = (uint2*)alloc((size_t)EE * 8);

  // setup: projection, converts, transpose, chunked-CSC build
  proj_w<<<dim3(128), dim3(128), 0, stream>>>(W, Wb);
  convert_mat2<<<dim3(128), dim3(256), 0, stream>>>(Om1, Om2, Om1b, Om2b);
  transpose_u<<<dim3((NN + 63) / 64), dim3(256), 0, stream>>>(U, Ub, NN);
  hipMemsetAsync(counts, 0, (size_t)NV * 4, stream);
  hist_k<<<dim3(EE / 256), dim3(256), 0, stream>>>(er, ec, counts);
  scan1<<<dim3(NB2), dim3(256), 0, stream>>>(counts, bsums);
  scan2<<<dim3(1), dim3(1024), 0, stream>>>(bsums, boffs);
  scan3<<<dim3(NB2), dim3(256), 0, stream>>>(counts, boffs, colptr, cursor);
  scatter_k<<<dim3(8 * (EE / 256)), dim3(256), 0, stream>>>(er, ec, ev, cursor, rv);

  // B = gather(Omega_1 @ U) + Omega_2 @ U  (Bb holds bf16 B); X_0 = B
  const int GB = (NTILES + 1) / 2;  // 1563 blocks, 2 tiles/block
  gemm_k<<<dim3(GB), dim3(256), 0, stream>>>(Om1b, Ub, Xwb);
  gemm_k<<<dim3(GB), dim3(256), 0, stream>>>(Om2b, Ub, Bb);
  spmm_k<0><<<dim3(NN / 16), dim3(256), 0, stream>>>(colptr, rv, (const u16*)Xwb,
                                                     Bb, (u32*)nullptr, (float*)nullptr);

  // 20 fixed-point iterations (X_0 = B lives in Bb for the first gemm)
  for (int it = 0; it < ITERS; ++it) {
    const u16* xsrc = (it == 0) ? (const u16*)Bb : (const u16*)Xb;
    gemm_k<<<dim3(GB), dim3(256), 0, stream>>>(Wb, xsrc, Xwb);
    if (it < ITERS - 1)
      spmm_k<1><<<dim3(NN / 16), dim3(256), 0, stream>>>(colptr, rv, (const u16*)Xwb,
                                                         Bb, Xb, (float*)nullptr);
    else
      spmm_k<2><<<dim3(NN / 16), dim3(256), 0, stream>>>(colptr, rv, (const u16*)Xwb,
                                                         Bb, (u32*)nullptr, out);
  }
}